// Round 2
// baseline (881.982 us; speedup 1.0000x reference)
//
#include <hip/hip_runtime.h>

#define E_EDGES 131072
#define D_IN 128
#define D_HID 512
#define D_OUT 128

typedef __bf16 bf16x8 __attribute__((ext_vector_type(8)));
typedef float f32x4 __attribute__((ext_vector_type(4)));

// round-to-nearest-even f32 -> bf16 bits (no NaN handling needed here)
__device__ __forceinline__ unsigned short f2bf(float f) {
    unsigned int u = __float_as_uint(f);
    unsigned int r = (u + 0x7FFFu + ((u >> 16) & 1u)) >> 16;
    return (unsigned short)r;
}

__global__ void zero_kernel(int* __restrict__ cnt) {
    int i = blockIdx.x * blockDim.x + threadIdx.x;
    if (i < E_EDGES) cnt[i] = 0;
}

__global__ void hist_kernel(const int* __restrict__ seg, int* __restrict__ cnt, int nnz) {
    int i = blockIdx.x * blockDim.x + threadIdx.x;
    int stride = gridDim.x * blockDim.x;
    for (; i < nnz; i += stride) {
        atomicAdd(&cnt[seg[i]], 1);
    }
}

// one block, 1024 threads; each thread scans 128 contiguous counts
__global__ void scan_kernel(const int* __restrict__ cnt, int* __restrict__ off,
                            int* __restrict__ cur) {
    __shared__ int lds[1024];
    const int t = threadIdx.x;
    const int base = t * 128;
    int s = 0;
    for (int j = 0; j < 128; ++j) s += cnt[base + j];
    lds[t] = s;
    __syncthreads();
    // Hillis-Steele inclusive scan over 1024 partials
    for (int d = 1; d < 1024; d <<= 1) {
        int v = (t >= d) ? lds[t - d] : 0;
        __syncthreads();
        lds[t] += v;
        __syncthreads();
    }
    int run = lds[t] - s;   // exclusive prefix for this chunk
    for (int j = 0; j < 128; ++j) {
        off[base + j] = run;
        cur[base + j] = run;
        run += cnt[base + j];
    }
    if (t == 1023) off[E_EDGES] = run;
}

__global__ void fill_kernel(const int* __restrict__ seg, int* __restrict__ cur,
                            int* __restrict__ csr, int nnz) {
    int i = blockIdx.x * blockDim.x + threadIdx.x;
    int stride = gridDim.x * blockDim.x;
    for (; i < nnz; i += stride) {
        int p = atomicAdd(&cur[seg[i]], 1);
        csr[p] = i;
    }
}

// W1 [128][512] fp32 -> w1b = bf16 W1^T [512][128]; W2 [512][128] -> w2b [128][512]
__global__ void convw_kernel(const float* __restrict__ W1, const float* __restrict__ W2,
                             unsigned short* __restrict__ w1b, unsigned short* __restrict__ w2b) {
    int i = blockIdx.x * blockDim.x + threadIdx.x;
    if (i < D_IN * D_HID) {
        int n = i >> 7, k = i & 127;                 // w1b[n][k]
        w1b[i] = f2bf(W1[(size_t)k * D_HID + n]);
    } else {
        int i2 = i - D_IN * D_HID;
        int n = i2 >> 9, k = i2 & 511;               // w2b[n][k]
        w2b[i2] = f2bf(W2[(size_t)k * D_OUT + n]);
    }
}

// Fused: gather-mean -> bf16 -> (mean@W1+b1, relu) -> (@W2+b2) -> out
// block = 256 threads (4 waves); each wave owns 16 edges (rows); tile = 64 edges.
__global__ __launch_bounds__(256) void fused_kernel(
    const float* __restrict__ x, const int* __restrict__ csr,
    const int* __restrict__ off, const unsigned short* __restrict__ w1b,
    const unsigned short* __restrict__ w2b, const float* __restrict__ b1,
    const float* __restrict__ b2, float* __restrict__ out)
{
    __shared__ unsigned short mean_lds[64 * 128];   // swizzled, 16 KB
    __shared__ unsigned short hslice[4][16 * 32];   // per-wave h K-slice, 4 KB

    const int tid  = threadIdx.x;
    const int lane = tid & 63;
    const int w    = tid >> 6;        // wave 0..3
    const int tile = blockIdx.x;      // 0..2047
    const int row0 = w * 16;

    // ---------------- gather mean ----------------
    for (int el = 0; el < 16; ++el) {
        const int row = row0 + el;
        const int eid = tile * 64 + row;
        const int beg = off[eid], end = off[eid + 1];
        const int n = end - beg;
        const int* ce = csr + beg;
        float s0x = 0.f, s0y = 0.f, s1x = 0.f, s1y = 0.f;
        float s2x = 0.f, s2y = 0.f, s3x = 0.f, s3y = 0.f;
        int j = 0;
        for (; j + 4 <= n; j += 4) {
            int i0 = ce[j], i1 = ce[j + 1], i2 = ce[j + 2], i3 = ce[j + 3];
            float2 v0 = *((const float2*)(x + (size_t)i0 * D_IN) + lane);
            float2 v1 = *((const float2*)(x + (size_t)i1 * D_IN) + lane);
            float2 v2 = *((const float2*)(x + (size_t)i2 * D_IN) + lane);
            float2 v3 = *((const float2*)(x + (size_t)i3 * D_IN) + lane);
            s0x += v0.x; s0y += v0.y; s1x += v1.x; s1y += v1.y;
            s2x += v2.x; s2y += v2.y; s3x += v3.x; s3y += v3.y;
        }
        for (; j < n; ++j) {
            int i0 = ce[j];
            float2 v0 = *((const float2*)(x + (size_t)i0 * D_IN) + lane);
            s0x += v0.x; s0y += v0.y;
        }
        float sx = (s0x + s1x) + (s2x + s3x);
        float sy = (s0y + s1y) + (s2y + s3y);
        const float scale = 1.0f / (float)(n > 0 ? n : 1);
        sx *= scale; sy *= scale;
        // write 2 bf16 as one dword; swizzle: flip 16B-chunk bits with row&7
        unsigned int byte = ((unsigned)(row * 256 + lane * 4)) ^ ((unsigned)(row & 7) << 4);
        *(unsigned int*)((char*)mean_lds + byte) =
            (unsigned)f2bf(sx) | ((unsigned)f2bf(sy) << 16);
    }
    // wave-private LDS: no barrier needed (each wave reads only its own rows)

    // ---------------- GEMMs ----------------
    const int lrow = lane & 15;
    const int lgrp = lane >> 4;

    bf16x8 afrag[4];
#pragma unroll
    for (int kk = 0; kk < 4; ++kk) {
        int row = row0 + lrow;
        unsigned int byte = ((unsigned)(row * 256 + kk * 64 + lgrp * 16)) ^ ((unsigned)(row & 7) << 4);
        afrag[kk] = *(const bf16x8*)((const char*)mean_lds + byte);
    }

    const f32x4 fzero = {0.f, 0.f, 0.f, 0.f};
    f32x4 acc2[8];
#pragma unroll
    for (int t = 0; t < 8; ++t) acc2[t] = fzero;

    unsigned short* hs = &hslice[w][0];

    for (int ntp = 0; ntp < 16; ++ntp) {
#pragma unroll
        for (int half = 0; half < 2; ++half) {
            const int nt = ntp * 2 + half;
            f32x4 acc = fzero;
#pragma unroll
            for (int kk = 0; kk < 4; ++kk) {
                const bf16x8 b = *(const bf16x8*)(w1b + (size_t)(nt * 16 + lrow) * 128 + kk * 32 + lgrp * 8);
                acc = __builtin_amdgcn_mfma_f32_16x16x32_bf16(afrag[kk], b, acc, 0, 0, 0);
            }
            const int hcol = nt * 16 + lrow;
            const float bias = b1[hcol];
#pragma unroll
            for (int r = 0; r < 4; ++r) {
                float v = acc[r] + bias;
                v = fmaxf(v, 0.f);
                const int rowD = lgrp * 4 + r;
                const int klocal = half * 16 + lrow;
                unsigned int byte = ((unsigned)(rowD * 64 + klocal * 2)) ^ ((unsigned)(rowD & 3) << 4);
                *(unsigned short*)((char*)hs + byte) = f2bf(v);
            }
        }
        // consume the 16x32 h slice as GEMM2 A-fragment (K-slice ntp)
        {
            unsigned int byte = ((unsigned)(lrow * 64 + lgrp * 16)) ^ ((unsigned)(lrow & 3) << 4);
            const bf16x8 a2 = *(const bf16x8*)((const char*)hs + byte);
#pragma unroll
            for (int nt2 = 0; nt2 < 8; ++nt2) {
                const bf16x8 b = *(const bf16x8*)(w2b + (size_t)(nt2 * 16 + lrow) * 512 + ntp * 32 + lgrp * 8);
                acc2[nt2] = __builtin_amdgcn_mfma_f32_16x16x32_bf16(a2, b, acc2[nt2], 0, 0, 0);
            }
        }
    }

    // ---------------- epilogue ----------------
#pragma unroll
    for (int nt2 = 0; nt2 < 8; ++nt2) {
        const int col = nt2 * 16 + lrow;
        const float bias = b2[col];
#pragma unroll
        for (int r = 0; r < 4; ++r) {
            const int row = tile * 64 + row0 + lgrp * 4 + r;
            out[(size_t)row * 128 + col] = acc2[nt2][r] + bias;
        }
    }
}

extern "C" void kernel_launch(void* const* d_in, const int* in_sizes, int n_in,
                              void* d_out, int out_size, void* d_ws, size_t ws_size,
                              hipStream_t stream)
{
    const float* x  = (const float*)d_in[0];
    const int* hyper = (const int*)d_in[1];
    const float* W1 = (const float*)d_in[2];
    const float* b1 = (const float*)d_in[3];
    const float* W2 = (const float*)d_in[4];
    const float* b2 = (const float*)d_in[5];
    const int nnz = in_sizes[0] / D_IN;
    const int* seg = hyper + nnz;   // hyperedge_index[1]

    // workspace map (non-overlapping; off needs E+1 ints):
    //   cnt [0x000000, 0x080000)   E ints
    //   off [0x080000, 0x100004)   E+1 ints   <-- previously overlapped cur!
    //   cur [0x100100, 0x180100)   E ints
    //   csr [0x180100, 0x980100)   NNZ ints (8 MB)
    //   w1b [0x980100, 0x9A0100)   128 KB bf16
    //   w2b [0x9A0100, 0x9C0100)   128 KB bf16
    char* ws = (char*)d_ws;
    int* cnt = (int*)(ws + 0x000000);
    int* off = (int*)(ws + 0x080000);
    int* cur = (int*)(ws + 0x100100);
    int* csr = (int*)(ws + 0x180100);
    unsigned short* w1b = (unsigned short*)(ws + 0x980100);
    unsigned short* w2b = (unsigned short*)(ws + 0x9A0100);
    float* out = (float*)d_out;

    hipLaunchKernelGGL(zero_kernel, dim3(E_EDGES / 256), dim3(256), 0, stream, cnt);
    hipLaunchKernelGGL(hist_kernel, dim3(2048), dim3(256), 0, stream, seg, cnt, nnz);
    hipLaunchKernelGGL(scan_kernel, dim3(1), dim3(1024), 0, stream, cnt, off, cur);
    hipLaunchKernelGGL(fill_kernel, dim3(2048), dim3(256), 0, stream, seg, cur, csr, nnz);
    hipLaunchKernelGGL(convw_kernel, dim3((D_IN * D_HID + D_HID * D_OUT) / 256), dim3(256), 0,
                       stream, W1, W2, w1b, w2b);
    hipLaunchKernelGGL(fused_kernel, dim3(E_EDGES / 64), dim3(256), 0, stream,
                       x, csr, off, w1b, w2b, b1, b2, out);
}

// Round 3
// 775.097 us; speedup vs baseline: 1.1379x; 1.1379x over previous
//
#include <hip/hip_runtime.h>

#define E_EDGES 131072
#define D_IN 128
#define D_HID 512
#define D_OUT 128

typedef __bf16 bf16x8 __attribute__((ext_vector_type(8)));
typedef float f32x4 __attribute__((ext_vector_type(4)));

// round-to-nearest-even f32 -> bf16 bits
__device__ __forceinline__ unsigned short f2bf(float f) {
    unsigned int u = __float_as_uint(f);
    unsigned int r = (u + 0x7FFFu + ((u >> 16) & 1u)) >> 16;
    return (unsigned short)r;
}

__global__ void zero_kernel(int* __restrict__ cnt) {
    int i = blockIdx.x * blockDim.x + threadIdx.x;   // 32768 threads, int4 each
    ((int4*)cnt)[i] = make_int4(0, 0, 0, 0);
}

__global__ void hist_kernel(const int* __restrict__ seg, int* __restrict__ cnt, int nnz) {
    int i = blockIdx.x * blockDim.x + threadIdx.x;
    if (i * 4 < nnz) {
        int4 s = ((const int4*)seg)[i];
        atomicAdd(&cnt[s.x], 1);
        atomicAdd(&cnt[s.y], 1);
        atomicAdd(&cnt[s.z], 1);
        atomicAdd(&cnt[s.w], 1);
    }
}

// 128 blocks x 256 threads; block b sums cnt ints [b*1024, b*1024+1023]
__global__ void blocksum_kernel(const int* __restrict__ cnt, int* __restrict__ bsum) {
    __shared__ int wsum[4];
    const int b = blockIdx.x, t = threadIdx.x;
    int4 c = ((const int4*)cnt)[b * 256 + t];
    int s = c.x + c.y + c.z + c.w;
    for (int d = 32; d; d >>= 1) s += __shfl_down(s, d);
    if ((t & 63) == 0) wsum[t >> 6] = s;
    __syncthreads();
    if (t == 0) bsum[b] = wsum[0] + wsum[1] + wsum[2] + wsum[3];
}

// 1 wave: exclusive-scan 128 block sums; also writes off[E_EDGES] = total
__global__ void bscan_kernel(const int* __restrict__ bsum, int* __restrict__ bpre,
                             int* __restrict__ off_last) {
    const int l = threadIdx.x;   // 0..63
    int a = bsum[2 * l], b = bsum[2 * l + 1];
    int s = a + b;
    for (int d = 1; d < 64; d <<= 1) {
        int u = __shfl_up(s, d);
        if (l >= d) s += u;
    }
    int excl = s - (a + b);
    bpre[2 * l] = excl;
    bpre[2 * l + 1] = excl + a;
    if (l == 63) off_last[0] = s;
}

// 128 blocks x 256 threads; rescan each 1024-chunk with block prefix; coalesced int4
__global__ void scan2_kernel(const int* __restrict__ cnt, const int* __restrict__ bpre,
                             int* __restrict__ off, int* __restrict__ cur) {
    __shared__ int wsum[4];
    const int b = blockIdx.x, t = threadIdx.x;
    const int gid = b * 256 + t;
    int4 c = ((const int4*)cnt)[gid];
    const int s = c.x + c.y + c.z + c.w;
    const int lane = t & 63, w = t >> 6;
    int incl = s;
    for (int d = 1; d < 64; d <<= 1) {
        int u = __shfl_up(incl, d);
        if (lane >= d) incl += u;
    }
    if (lane == 63) wsum[w] = incl;
    __syncthreads();
    int woff = 0;
    for (int i = 0; i < w; ++i) woff += wsum[i];
    const int base = bpre[b] + woff + (incl - s);
    int4 o;
    o.x = base;
    o.y = base + c.x;
    o.z = base + c.x + c.y;
    o.w = base + c.x + c.y + c.z;
    ((int4*)off)[gid] = o;
    ((int4*)cur)[gid] = o;
}

__global__ void fill_kernel(const int* __restrict__ seg, int* __restrict__ cur,
                            int* __restrict__ csr, int nnz) {
    int i = blockIdx.x * blockDim.x + threadIdx.x;
    if (i * 4 < nnz) {
        int4 s = ((const int4*)seg)[i];
        int p0 = atomicAdd(&cur[s.x], 1);
        int p1 = atomicAdd(&cur[s.y], 1);
        int p2 = atomicAdd(&cur[s.z], 1);
        int p3 = atomicAdd(&cur[s.w], 1);
        csr[p0] = i * 4;
        csr[p1] = i * 4 + 1;
        csr[p2] = i * 4 + 2;
        csr[p3] = i * 4 + 3;
    }
}

// W1 [128][512] fp32 -> w1b = bf16 W1^T [512][128]; W2 [512][128] -> w2b [128][512]
__global__ void convw_kernel(const float* __restrict__ W1, const float* __restrict__ W2,
                             unsigned short* __restrict__ w1b, unsigned short* __restrict__ w2b) {
    int i = blockIdx.x * blockDim.x + threadIdx.x;
    if (i < D_IN * D_HID) {
        int n = i >> 7, k = i & 127;                 // w1b[n][k]
        w1b[i] = f2bf(W1[(size_t)k * D_HID + n]);
    } else {
        int i2 = i - D_IN * D_HID;
        int n = i2 >> 9, k = i2 & 511;               // w2b[n][k]
        w2b[i2] = f2bf(W2[(size_t)k * D_OUT + n]);
    }
}

// Fused: gather-mean -> bf16 -> (mean@W1+b1, relu) -> (@W2+b2) -> out
// block = 256 threads (4 waves); each wave owns 16 edges; tile = 64 edges.
__global__ __launch_bounds__(256) void fused_kernel(
    const float* __restrict__ x, const int* __restrict__ csr,
    const int* __restrict__ off, const unsigned short* __restrict__ w1b,
    const unsigned short* __restrict__ w2b, const float* __restrict__ b1,
    const float* __restrict__ b2, float* __restrict__ out)
{
    __shared__ unsigned short mean_lds[64 * 128];   // swizzled, 16 KB
    __shared__ unsigned short hslice[4][16 * 32];   // per-wave h K-slice, 4 KB

    const int tid  = threadIdx.x;
    const int lane = tid & 63;
    const int w    = tid >> 6;        // wave 0..3
    const int tile = blockIdx.x;      // 0..2047
    const int row0 = w * 16;

    // ---------------- gather mean ----------------
    const int c  = lane & 31;         // float4 column (cols 4c..4c+3)
    const int rr = lane >> 5;         // row parity within pair
    const char* xb = (const char*)x + c * 16;

    // preload the 17 offsets this wave needs
    int oreg = off[tile * 64 + row0 + (lane < 17 ? lane : 16)];

    for (int el = 0; el < 16; ++el) {
        const int row = row0 + el;
        const int beg = __shfl(oreg, el);
        const int end = __shfl(oreg, el + 1);
        const int n = end - beg;
        const int* ce = csr + beg;
        f32x4 a0 = {0.f, 0.f, 0.f, 0.f}, a1 = a0, a2 = a0, a3 = a0;
        int j = 0;
        for (; j + 8 <= n; j += 8) {
            int i0 = ce[j + 0 + rr];
            int i1 = ce[j + 2 + rr];
            int i2 = ce[j + 4 + rr];
            int i3 = ce[j + 6 + rr];
            f32x4 v0 = *(const f32x4*)(xb + (size_t)i0 * 512);
            f32x4 v1 = *(const f32x4*)(xb + (size_t)i1 * 512);
            f32x4 v2 = *(const f32x4*)(xb + (size_t)i2 * 512);
            f32x4 v3 = *(const f32x4*)(xb + (size_t)i3 * 512);
            a0 += v0; a1 += v1; a2 += v2; a3 += v3;
        }
        for (; j < n; j += 2) {
            const int jr = j + rr;
            const bool valid = jr < n;
            int idx = ce[valid ? jr : n - 1];
            f32x4 v = *(const f32x4*)(xb + (size_t)idx * 512);
            if (valid) a0 += v;
        }
        f32x4 tot = (a0 + a1) + (a2 + a3);
        tot[0] += __shfl_xor(tot[0], 32);
        tot[1] += __shfl_xor(tot[1], 32);
        tot[2] += __shfl_xor(tot[2], 32);
        tot[3] += __shfl_xor(tot[3], 32);
        const float scale = 1.0f / (float)(n > 0 ? n : 1);
        if (lane < 32) {
            unsigned int d0 = (unsigned)f2bf(tot[0] * scale) | ((unsigned)f2bf(tot[1] * scale) << 16);
            unsigned int d1 = (unsigned)f2bf(tot[2] * scale) | ((unsigned)f2bf(tot[3] * scale) << 16);
            unsigned int byte = ((unsigned)(row * 256 + c * 8)) ^ ((unsigned)(row & 7) << 4);
            uint2* p = (uint2*)((char*)mean_lds + byte);
            *p = make_uint2(d0, d1);
        }
    }
    // wave-private LDS: no barrier needed

    // ---------------- GEMMs ----------------
    const int lrow = lane & 15;
    const int lgrp = lane >> 4;

    bf16x8 afrag[4];
#pragma unroll
    for (int kk = 0; kk < 4; ++kk) {
        int row = row0 + lrow;
        unsigned int byte = ((unsigned)(row * 256 + kk * 64 + lgrp * 16)) ^ ((unsigned)(row & 7) << 4);
        afrag[kk] = *(const bf16x8*)((const char*)mean_lds + byte);
    }

    const f32x4 fzero = {0.f, 0.f, 0.f, 0.f};
    f32x4 acc2[8];
#pragma unroll
    for (int t = 0; t < 8; ++t) acc2[t] = fzero;

    unsigned short* hs = &hslice[w][0];

    for (int ntp = 0; ntp < 16; ++ntp) {
#pragma unroll
        for (int half = 0; half < 2; ++half) {
            const int nt = ntp * 2 + half;
            f32x4 acc = fzero;
#pragma unroll
            for (int kk = 0; kk < 4; ++kk) {
                const bf16x8 b = *(const bf16x8*)(w1b + (size_t)(nt * 16 + lrow) * 128 + kk * 32 + lgrp * 8);
                acc = __builtin_amdgcn_mfma_f32_16x16x32_bf16(afrag[kk], b, acc, 0, 0, 0);
            }
            const int hcol = nt * 16 + lrow;
            const float bias = b1[hcol];
#pragma unroll
            for (int r = 0; r < 4; ++r) {
                float v = acc[r] + bias;
                v = fmaxf(v, 0.f);
                const int rowD = lgrp * 4 + r;
                const int klocal = half * 16 + lrow;
                unsigned int byte = ((unsigned)(rowD * 64 + klocal * 2)) ^ ((unsigned)(rowD & 3) << 4);
                *(unsigned short*)((char*)hs + byte) = f2bf(v);
            }
        }
        // consume the 16x32 h slice as GEMM2 A-fragment (K-slice ntp)
        {
            unsigned int byte = ((unsigned)(lrow * 64 + lgrp * 16)) ^ ((unsigned)(lrow & 3) << 4);
            const bf16x8 a2 = *(const bf16x8*)((const char*)hs + byte);
#pragma unroll
            for (int nt2 = 0; nt2 < 8; ++nt2) {
                const bf16x8 b = *(const bf16x8*)(w2b + (size_t)(nt2 * 16 + lrow) * 512 + ntp * 32 + lgrp * 8);
                acc2[nt2] = __builtin_amdgcn_mfma_f32_16x16x32_bf16(a2, b, acc2[nt2], 0, 0, 0);
            }
        }
    }

    // ---------------- epilogue ----------------
#pragma unroll
    for (int nt2 = 0; nt2 < 8; ++nt2) {
        const int col = nt2 * 16 + lrow;
        const float bias = b2[col];
#pragma unroll
        for (int r = 0; r < 4; ++r) {
            const int row = tile * 64 + row0 + lgrp * 4 + r;
            out[(size_t)row * 128 + col] = acc2[nt2][r] + bias;
        }
    }
}

extern "C" void kernel_launch(void* const* d_in, const int* in_sizes, int n_in,
                              void* d_out, int out_size, void* d_ws, size_t ws_size,
                              hipStream_t stream)
{
    const float* x  = (const float*)d_in[0];
    const int* hyper = (const int*)d_in[1];
    const float* W1 = (const float*)d_in[2];
    const float* b1 = (const float*)d_in[3];
    const float* W2 = (const float*)d_in[4];
    const float* b2 = (const float*)d_in[5];
    const int nnz = in_sizes[0] / D_IN;
    const int* seg = hyper + nnz;   // hyperedge_index[1] (harness converts int64->int32)

    // workspace map (non-overlapping; off needs E+1 ints):
    char* ws = (char*)d_ws;
    int* cnt  = (int*)(ws + 0x000000);           // E ints
    int* off  = (int*)(ws + 0x080000);           // E+1 ints
    int* cur  = (int*)(ws + 0x100100);           // E ints
    int* csr  = (int*)(ws + 0x180100);           // NNZ ints (8 MB)
    unsigned short* w1b = (unsigned short*)(ws + 0x980100);  // 128 KB
    unsigned short* w2b = (unsigned short*)(ws + 0x9A0100);  // 128 KB
    int* bsum = (int*)(ws + 0x9C0100);           // 128 ints
    int* bpre = (int*)(ws + 0x9C0300);           // 128 ints
    float* out = (float*)d_out;

    hipLaunchKernelGGL(zero_kernel, dim3(128), dim3(256), 0, stream, cnt);
    hipLaunchKernelGGL(hist_kernel, dim3(nnz / 1024), dim3(256), 0, stream, seg, cnt, nnz);
    hipLaunchKernelGGL(blocksum_kernel, dim3(128), dim3(256), 0, stream, cnt, bsum);
    hipLaunchKernelGGL(bscan_kernel, dim3(1), dim3(64), 0, stream, bsum, bpre, off + E_EDGES);
    hipLaunchKernelGGL(scan2_kernel, dim3(128), dim3(256), 0, stream, cnt, bpre, off, cur);
    hipLaunchKernelGGL(fill_kernel, dim3(nnz / 1024), dim3(256), 0, stream, seg, cur, csr, nnz);
    hipLaunchKernelGGL(convw_kernel, dim3((D_IN * D_HID + D_HID * D_OUT) / 256), dim3(256), 0,
                       stream, W1, W2, w1b, w2b);
    hipLaunchKernelGGL(fused_kernel, dim3(E_EDGES / 64), dim3(256), 0, stream,
                       x, csr, off, w1b, w2b, b1, b2, out);
}